// Round 6
// baseline (402.994 us; speedup 1.0000x reference)
//
#include <hip/hip_runtime.h>
#include <cstdint>

// ShortTermLSTM on MI355X: batched LSTM via f16 MFMA, fully in-register cell.
// R1 (569us): 4x 16x16x32 MFMA hi/lo pairs, K=128, absmax 1.95e-3.
// R2/R3 (failed): legacy 16x16x16f16 B-layout is NOT k=quad*4+j. Reverted.
// R4 (444us): s_x removed, launch_bounds(256,3), 3 blocks/CU co-resident.
// R5 (370us): h stored f16-only -> 5 MFMAs/tile. VALU 54 / MFMA 25.5.
// R6: B columns PERMUTED so each 16-col tile = 4 complete units (n_loc=4u+g,
//   orig row = g*100 + tile*4 + u). After MFMA, a 4x4 DPP quad_perm transpose
//   (VALU-only, lanes^1 then ^2) puts all 4 gates of unit (s,j) in one lane ->
//   cell computed in registers. s_g deleted; s_A ping-pong (write h(t+1) to
//   the other buffer) -> ONE barrier per timestep (the data-dependency minimum).
//
// gates[S=16,400] = A[16,128] x B[128,400] per timestep:
//   A_hi cols   0.. 99 : f16(h)              -> B = f16(W_hh)
//   A_hi cols 100..103 : x_hi                -> B = f16(W_ih)      (=W_hi)
//   A_lo cols 100..103 : x_lo                -> B = f16(W_ih)
//   A_lo cols 104..107 : x_hi (W_lo route)   -> B = f16(W_ih-W_hi) (=W_lo)
//   A_hi col  108      : 1.0                 -> B = f16(b)         (=b_hi)
//   A_lo col  109      : 1.0                 -> B = f16(b-b_hi)    (=b_lo)
// Per tile: 4 MFMAs on A_hi (kc0..3) + 1 on A_lo (kc3). c in fp32 regs.

#define H_UNITS 100
#define T_STEPS 128
#define S_BLK   16
#define NSEQ    12288
#define NBLK    (NSEQ / S_BLK)   // 768
#define NTILE   25               // 100 units / 4 per tile
#define KSTR    136              // LDS A row stride (ushorts): 8-phase-ideal b128 reads

typedef __attribute__((ext_vector_type(8))) _Float16 halfx8;
typedef __attribute__((ext_vector_type(8))) unsigned short ushortx8;
typedef __attribute__((ext_vector_type(4))) float floatx4;

__device__ __forceinline__ unsigned short f32_to_f16u(float x) {
    _Float16 h = (_Float16)x;                       // v_cvt_f16_f32 (RNE)
    return __builtin_bit_cast(unsigned short, h);
}
__device__ __forceinline__ float f16u_to_f32(unsigned short u) {
    _Float16 h = __builtin_bit_cast(_Float16, u);
    return (float)h;
}
__device__ __forceinline__ float fsigm(float x) {
    return __builtin_amdgcn_rcpf(1.0f + __expf(-x));
}
__device__ __forceinline__ float ftanh(float x) {
    // 1 - 2/(e^{2x}+1); exp->inf handled correctly (rcp(inf)=0)
    return 1.0f - 2.0f * __builtin_amdgcn_rcpf(1.0f + __expf(2.0f * x));
}
// DPP quad_perm within consecutive 4-lane groups (pure VALU, no LDS pipe).
__device__ __forceinline__ float dpp_xor1(float v) {   // lanes [1,0,3,2]
    return __builtin_bit_cast(float, __builtin_amdgcn_update_dpp(
        0, __builtin_bit_cast(int, v), 0xB1, 0xF, 0xF, true));
}
__device__ __forceinline__ float dpp_xor2(float v) {   // lanes [2,3,0,1]
    return __builtin_bit_cast(float, __builtin_amdgcn_update_dpp(
        0, __builtin_bit_cast(int, v), 0x4E, 0xF, 0xF, true));
}

// ---------------------------------------------------------------------------
// Prep: pack B into MFMA B-fragment order WITH the unit-interleaved column
// permutation: tile column n_loc = 4*u + g  <->  original row g*100 + tile*4 + u.
//   frag element: Bpack[(tile*4+kc)*64 + lane][j] = B[k = kc*32+quad*8+j][n_loc = lane&15]
// ---------------------------------------------------------------------------
__global__ void lstm_prep_pack(const float* __restrict__ W_ih,
                               const float* __restrict__ W_hh,
                               const float* __restrict__ b_ih,
                               const float* __restrict__ b_hh,
                               ushortx8* __restrict__ Bpack) {
    int t = blockIdx.x * 256 + threadIdx.x;   // (tile,kc,lane) flattened: 25*4*64 = 6400
    if (t >= NTILE * 4 * 64) return;
    int lane = t & 63;
    int kc   = (t >> 6) & 3;
    int tile = t >> 8;
    int nloc = lane & 15;
    int n  = (nloc & 3) * 100 + tile * 4 + (nloc >> 2);   // permuted gate-row index
    int k0 = kc * 32 + ((lane >> 4) & 3) * 8;
    ushortx8 v;
#pragma unroll
    for (int j = 0; j < 8; ++j) {
        int k = k0 + j;
        unsigned short w = 0;
        if (k < 100) {
            w = f32_to_f16u(W_hh[n * 100 + k]);
        } else if (k < 104) {
            w = f32_to_f16u(W_ih[n * 4 + (k - 100)]);
        } else if (k < 108) {
            float wf = W_ih[n * 4 + (k - 104)];
            unsigned short hi = f32_to_f16u(wf);
            w = f32_to_f16u(wf - f16u_to_f32(hi));
        } else if (k == 108) {
            float b = b_ih[n] + b_hh[n];
            w = f32_to_f16u(b);
        } else if (k == 109) {
            float b = b_ih[n] + b_hh[n];
            unsigned short hi = f32_to_f16u(b);
            w = f32_to_f16u(b - f16u_to_f32(hi));
        }
        v[j] = w;
    }
    Bpack[t] = v;
}

// ---------------------------------------------------------------------------
// Main: one block = 16 sequences, full T loop. 4 waves; wave w owns tiles
// {w, w+4, ...} (wave0: 7, others 6 -> 1600 units over 256 lanes, balanced).
// B frags persist in regs. launch_bounds(256,3): 3 blocks/CU co-resident.
// ---------------------------------------------------------------------------
__global__ void __launch_bounds__(256, 3)
lstm_main(const float* __restrict__ x, const ushortx8* __restrict__ Bpack,
          float* __restrict__ out) {
    __shared__ __align__(16) unsigned short s_A[2][2 * 16 * KSTR];   // ping-pong, 2 x 8704 B

    const int tid  = threadIdx.x;
    const int lane = tid & 63;
    const int wave = tid >> 6;
    const int seq0 = blockIdx.x * S_BLK;
    const int m    = lane & 15;
    const int quad = lane >> 4;

    // ---- B fragments: global -> regs, once
    halfx8 bfrag[7][4];
#pragma unroll
    for (int it = 0; it < 7; ++it) {
        int tile = wave + it * 4;
        if (tile < NTILE) {
#pragma unroll
            for (int kc = 0; kc < 4; ++kc)
                bfrag[it][kc] = __builtin_bit_cast(halfx8, Bpack[(tile * 4 + kc) * 64 + lane]);
        }
    }

    // refresh-thread x pointer (valid for tid < 128): (s = tid&15, cc = tid>>4)
    const int rs = tid & 15, rc = tid >> 4;
    const float* xb = x + (size_t)(seq0 + rs) * (T_STEPS * 4) + (rc & 3);

    // ---- zero both buffers (h(0)=0; pad cols and A_lo cols 0..99 stay 0)
    for (int i = tid; i < (2 * 2 * 16 * KSTR) / 2; i += 256)
        ((unsigned int*)s_A)[i] = 0u;
    float x0 = 0.0f;
    if (tid < 128) x0 = xb[0];
    __syncthreads();
    // ---- x(t=0) into buf0; constant bias-select cols into BOTH buffers
    if (tid < 128) {
        unsigned short hi = f32_to_f16u(x0);
        if (rc < 4) {
            s_A[0][rs * KSTR + 100 + rc]        = hi;                                // A_hi = x_hi
            s_A[0][(16 + rs) * KSTR + 100 + rc] = f32_to_f16u(x0 - f16u_to_f32(hi)); // A_lo = x_lo
        } else {
            s_A[0][(16 + rs) * KSTR + 100 + rc] = hi;                                // A_lo = x_hi (W_lo)
        }
    } else if (tid < 160) {
        int d = tid - 128;                     // 0..31: (buf, s) for col108
        s_A[d >> 4][(d & 15) * KSTR + 108] = 0x3C00;          // A_hi col108 = 1.0
    } else if (tid < 192) {
        int d = tid - 160;                     // 0..31: (buf, s) for col109
        s_A[d >> 4][(16 + (d & 15)) * KSTR + 109] = 0x3C00;   // A_lo col109 = 1.0
    }

    float c_reg[7];
#pragma unroll
    for (int it = 0; it < 7; ++it) c_reg[it] = 0.0f;

    // cell-lane constants: after transpose, lane holds gates of unit
    // (s = quad*4 + (lane&3), j = tile*4 + ((lane>>2)&3))
    const bool b0 = (lane & 1) != 0;
    const bool b1 = (lane & 2) != 0;
    const int  u_loc  = (lane >> 2) & 3;
    const int  s_cell = quad * 4 + (lane & 3);

    const int aOffHi = m * KSTR + quad * 8;
    const int aOffLo = (16 + m) * KSTR + quad * 8 + 96;

    for (int t = 0; t < T_STEPS; ++t) {
        const int bR = t & 1, bW = bR ^ 1;
        // prefetch x(t+1) — issued before MFMA phase to hide latency
        float xnext = 0.0f;
        if (tid < 128) {
            int tn = t + 1; if (tn > T_STEPS - 1) tn = T_STEPS - 1;
            xnext = xb[tn * 4];
        }
        __syncthreads();   // h(t)/x(t) writes to buf[bR] complete (ONE barrier/step)

        const unsigned short* base = s_A[bR];
        unsigned short* baseW = s_A[bW];
        halfx8 ah[4], al3;
#pragma unroll
        for (int kc = 0; kc < 4; ++kc)
            ah[kc] = *(const halfx8*)(base + aOffHi + kc * 32);   // ds_read_b128
        al3 = *(const halfx8*)(base + aOffLo);

        const bool last = (t == T_STEPS - 1);
#pragma unroll
        for (int it = 0; it < 7; ++it) {
            int tile = wave + it * 4;
            if (tile < NTILE) {
                floatx4 acc = {0.0f, 0.0f, 0.0f, 0.0f};
#pragma unroll
                for (int kc = 0; kc < 4; ++kc)
                    acc = __builtin_amdgcn_mfma_f32_16x16x32_f16(ah[kc], bfrag[it][kc], acc, 0, 0, 0);
                acc = __builtin_amdgcn_mfma_f32_16x16x32_f16(al3, bfrag[it][3], acc, 0, 0, 0);
                // acc: reg r = gate (lane&3's col group) ... 4x4 transpose in the
                // (lane&3) x reg space via DPP quad_perm: P[l][r] = M[r][l].
                float m0 = acc[0], m1 = acc[1], m2 = acc[2], m3 = acc[3];
                float X = dpp_xor1(b0 ? m0 : m1);
                float Y = dpp_xor1(b0 ? m2 : m3);
                float n0 = b0 ? X : m0, n1 = b0 ? m1 : X;
                float n2 = b0 ? Y : m2, n3 = b0 ? m3 : Y;
                float Z = dpp_xor2(b1 ? n0 : n2);
                float V = dpp_xor2(b1 ? n1 : n3);
                float p0 = b1 ? Z : n0, p1 = b1 ? V : n1;    // i, f
                float p2 = b1 ? n2 : Z, p3 = b1 ? n3 : V;    // g, o
                // LSTM cell, all in registers
                float c = fsigm(p1) * c_reg[it] + fsigm(p0) * ftanh(p2);
                c_reg[it] = c;
                float h = fsigm(p3) * ftanh(c);
                int j = tile * 4 + u_loc;
                if (!last) {
                    baseW[s_cell * KSTR + j] = f32_to_f16u(h);    // h(t+1) -> other buffer
                } else {
                    out[(size_t)(seq0 + s_cell) * H_UNITS + j] = h;
                }
            }
        }
        if (tid < 128 && !last) {             // x(t+1) cols 100..107 -> other buffer
            unsigned short hi = f32_to_f16u(xnext);
            if (rc < 4) {
                baseW[rs * KSTR + 100 + rc]        = hi;
                baseW[(16 + rs) * KSTR + 100 + rc] = f32_to_f16u(xnext - f16u_to_f32(hi));
            } else {
                baseW[(16 + rs) * KSTR + 100 + rc] = hi;
            }
        }
    }
}

extern "C" void kernel_launch(void* const* d_in, const int* in_sizes, int n_in,
                              void* d_out, int out_size, void* d_ws, size_t ws_size,
                              hipStream_t stream) {
    const float* x    = (const float*)d_in[0];   // [4096,3,128,4]
    const float* W_ih = (const float*)d_in[1];   // [400,4]
    const float* W_hh = (const float*)d_in[2];   // [400,100]
    const float* b_ih = (const float*)d_in[3];   // [400]
    const float* b_hh = (const float*)d_in[4];   // [400]
    ushortx8* Bpack = (ushortx8*)d_ws;           // 25*4*64*16 B = 102,400 B

    lstm_prep_pack<<<25, 256, 0, stream>>>(W_ih, W_hh, b_ih, b_hh, Bpack);
    lstm_main<<<NBLK, 256, 0, stream>>>(x, Bpack, (float*)d_out);
}

// Round 7
// 396.181 us; speedup vs baseline: 1.0172x; 1.0172x over previous
//
#include <hip/hip_runtime.h>
#include <cstdint>

// ShortTermLSTM on MI355X: batched LSTM via f16 MFMA, hi/lo split recurrence.
// R1 (569us): 4x 16x16x32 MFMA hi/lo pairs, K=128, absmax 1.95e-3.
// R2/R3 (failed): legacy 16x16x16f16 B-layout != k=quad*4+j. Reverted.
// R4 (444us): s_x removed, global x prefetch.
// R5 (370us): h f16-only -> 5 MFMAs/tile. VALU 54 / MFMA 25.5 / occ 29%.
// R6 (403us, reverted): DPP-transpose in-register cell — +77us VALU. Also
//   revealed (256,3) never engaged: 84 VGPR + 112 AGPR-frags = 196 > 170.
// R7: make 3 blocks/CU real. kc0 B-frags -> LDS (-28 regs => 168 <= 170);
//   s_g -> f16 [n][s] GSTR=20 (16,000 B). LDS total 50,304 B -> 3 blocks/CU;
//   grid 768 = 3x256 exactly -> single balanced round, no half-occupancy tail.
//
// gates[S=16,400] = A[16,128] x B[128,400] per timestep:
//   A_hi cols   0.. 99 : f16(h)              -> B = f16(W_hh)
//   A_hi cols 100..103 : x_hi                -> B = f16(W_ih)      (=W_hi)
//   A_lo cols 100..103 : x_lo                -> B = f16(W_ih)
//   A_lo cols 104..107 : x_hi (W_lo route)   -> B = f16(W_ih-W_hi) (=W_lo)
//   A_hi col  108      : 1.0                 -> B = f16(b)         (=b_hi)
//   A_lo col  109      : 1.0                 -> B = f16(b-b_hi)    (=b_lo)
// Per tile: 4 MFMAs on A_hi (kc0..3) + 1 on A_lo (kc3). c in fp32 regs.

#define H_UNITS 100
#define T_STEPS 128
#define S_BLK   16
#define NSEQ    12288
#define NBLK    (NSEQ / S_BLK)   // 768
#define NTILE   25               // 400 / 16
#define KSTR    136              // LDS A row stride (ushorts): 8-phase-ideal b128 reads
#define GSTR    20               // f16 gate stride per n-row (ushorts): 2-way-max banking

typedef __attribute__((ext_vector_type(8))) _Float16 halfx8;
typedef __attribute__((ext_vector_type(8))) unsigned short ushortx8;
typedef __attribute__((ext_vector_type(4))) float floatx4;
typedef __attribute__((ext_vector_type(2))) unsigned int uintx2;

__device__ __forceinline__ unsigned short f32_to_f16u(float x) {
    _Float16 h = (_Float16)x;                       // v_cvt_f16_f32 (RNE)
    return __builtin_bit_cast(unsigned short, h);
}
__device__ __forceinline__ float f16u_to_f32(unsigned short u) {
    _Float16 h = __builtin_bit_cast(_Float16, u);
    return (float)h;
}
__device__ __forceinline__ float fsigm(float x) {
    return __builtin_amdgcn_rcpf(1.0f + __expf(-x));
}
__device__ __forceinline__ float ftanh(float x) {
    // 1 - 2/(e^{2x}+1); exp->inf handled correctly (rcp(inf)=0)
    return 1.0f - 2.0f * __builtin_amdgcn_rcpf(1.0f + __expf(2.0f * x));
}

// ---------------------------------------------------------------------------
// Prep: pack B into MFMA B-fragment order: Bpack[tile][kc][lane][j] (8 f16 = 16B)
//   n = tile*16 + (lane&15),  k = kc*32 + (lane>>4)*8 + j      (VERIFIED in R1)
// ---------------------------------------------------------------------------
__global__ void lstm_prep_pack(const float* __restrict__ W_ih,
                               const float* __restrict__ W_hh,
                               const float* __restrict__ b_ih,
                               const float* __restrict__ b_hh,
                               ushortx8* __restrict__ Bpack) {
    int t = blockIdx.x * 256 + threadIdx.x;   // (tile,kc,lane) flattened: 25*4*64 = 6400
    if (t >= NTILE * 4 * 64) return;
    int lane = t & 63;
    int kc   = (t >> 6) & 3;
    int tile = t >> 8;
    int n  = tile * 16 + (lane & 15);
    int k0 = kc * 32 + ((lane >> 4) & 3) * 8;
    ushortx8 v;
#pragma unroll
    for (int j = 0; j < 8; ++j) {
        int k = k0 + j;
        unsigned short w = 0;
        if (k < 100) {
            w = f32_to_f16u(W_hh[n * 100 + k]);
        } else if (k < 104) {
            w = f32_to_f16u(W_ih[n * 4 + (k - 100)]);
        } else if (k < 108) {
            float wf = W_ih[n * 4 + (k - 104)];
            unsigned short hi = f32_to_f16u(wf);
            w = f32_to_f16u(wf - f16u_to_f32(hi));
        } else if (k == 108) {
            float b = b_ih[n] + b_hh[n];
            w = f32_to_f16u(b);
        } else if (k == 109) {
            float b = b_ih[n] + b_hh[n];
            unsigned short hi = f32_to_f16u(b);
            w = f32_to_f16u(b - f16u_to_f32(hi));
        }
        v[j] = w;
    }
    Bpack[t] = v;
}

// ---------------------------------------------------------------------------
// Main: one block = 16 sequences, full T loop. 4 waves; wave w owns N-tiles
// {w, w+4, ...}. kc1..3 B frags in regs (84); kc0 frags in LDS.
// launch_bounds(256,3): 168 total regs -> 3 waves/SIMD -> 3 blocks/CU ->
// all 768 blocks co-resident in one balanced round.
// ---------------------------------------------------------------------------
__global__ void __launch_bounds__(256, 3)
lstm_main(const float* __restrict__ x, const ushortx8* __restrict__ Bpack,
          float* __restrict__ out) {
    __shared__ __align__(16) unsigned short s_A[2 * 16 * KSTR];      //  8704 B (A_hi | A_lo)
    __shared__ __align__(16) unsigned short s_g16[400 * GSTR];       // 16000 B, f16 gates [n][s]
    __shared__ __align__(16) ushortx8       s_Bk0[NTILE * 64];       // 25600 B, kc0 B-frags

    const int tid  = threadIdx.x;
    const int lane = tid & 63;
    const int wave = tid >> 6;
    const int seq0 = blockIdx.x * S_BLK;
    const int m    = lane & 15;
    const int quad = lane >> 4;

    // ---- B fragments kc1..3: global -> regs, once (84 regs/wave)
    halfx8 bfrag[7][3];
#pragma unroll
    for (int it = 0; it < 7; ++it) {
        int tile = wave + it * 4;
        if (tile < NTILE) {
#pragma unroll
            for (int kc = 0; kc < 3; ++kc)   // original kc = kc+1
                bfrag[it][kc] = __builtin_bit_cast(halfx8, Bpack[(tile * 4 + kc + 1) * 64 + lane]);
        }
    }
    // ---- kc0 B-frags: global -> LDS, once
    for (int i = tid; i < NTILE * 64; i += 256)
        s_Bk0[i] = Bpack[(i >> 6) * 256 + (i & 63)];

    // refresh-thread x pointer (valid for tid < 128): (s = tid&15, cc = tid>>4)
    const int rs = tid & 15, rc = tid >> 4;
    const float* xb = x + (size_t)(seq0 + rs) * (T_STEPS * 4) + (rc & 3);

    // ---- zero A (h(0)=0; pad cols and A_lo cols 0..99 stay 0 forever)
    for (int i = tid; i < (2 * 16 * KSTR) / 2; i += 256)
        ((unsigned int*)s_A)[i] = 0u;
    float x0 = 0.0f;
    if (tid < 128) x0 = xb[0];
    __syncthreads();
    // ---- init x(t=0) cols + constant bias-select cols
    if (tid < 128) {
        unsigned short hi = f32_to_f16u(x0);
        if (rc < 4) {
            s_A[rs * KSTR + 100 + rc]        = hi;                                // A_hi = x_hi
            s_A[(16 + rs) * KSTR + 100 + rc] = f32_to_f16u(x0 - f16u_to_f32(hi)); // A_lo = x_lo
        } else {
            s_A[(16 + rs) * KSTR + 100 + rc] = hi;                                // A_lo = x_hi (W_lo)
        }
    } else if (tid < 144) {
        s_A[(tid - 128) * KSTR + 108] = 0x3C00;        // A_hi col108 = 1.0 (bias hi)
    } else if (tid < 160) {
        s_A[(16 + tid - 144) * KSTR + 109] = 0x3C00;   // A_lo col109 = 1.0 (bias lo)
    }

    float c_reg[6];
#pragma unroll
    for (int u = 0; u < 6; ++u) c_reg[u] = 0.0f;
    float c6 = 0.0f;

    const unsigned short* aHi  = &s_A[m * KSTR + quad * 8];
    const unsigned short* aLo3 = &s_A[(16 + m) * KSTR + quad * 8 + 96];   // kc3 of A_lo

    const int us = tid & 15;     // epilogue unit s
    const int j0 = tid >> 4;     // epilogue unit j base (j = j0 + 16u)

    for (int t = 0; t < T_STEPS; ++t) {
        // prefetch x(t+1) — issued before the MFMA phase to hide latency
        float xnext = 0.0f;
        if (tid < 128) {
            int tn = t + 1; if (tn > T_STEPS - 1) tn = T_STEPS - 1;
            xnext = xb[tn * 4];
        }
        __syncthreads();   // barrier 1: A(t) ready (also covers s_Bk0/x0 at t=0)
        halfx8 ah[4], al3;
#pragma unroll
        for (int kc = 0; kc < 4; ++kc)
            ah[kc] = *(const halfx8*)(aHi + kc * 32);   // ds_read_b128
        al3 = *(const halfx8*)aLo3;                     // ds_read_b128 (kc3 lo)
#pragma unroll
        for (int it = 0; it < 7; ++it) {
            int tile = wave + it * 4;
            if (tile < NTILE) {
                halfx8 b0 = __builtin_bit_cast(halfx8, s_Bk0[tile * 64 + lane]);  // kc0 frag
                floatx4 acc = {0.0f, 0.0f, 0.0f, 0.0f};
                acc = __builtin_amdgcn_mfma_f32_16x16x32_f16(ah[0], b0,           acc, 0, 0, 0);
                acc = __builtin_amdgcn_mfma_f32_16x16x32_f16(ah[1], bfrag[it][0], acc, 0, 0, 0);
                acc = __builtin_amdgcn_mfma_f32_16x16x32_f16(ah[2], bfrag[it][1], acc, 0, 0, 0);
                acc = __builtin_amdgcn_mfma_f32_16x16x32_f16(ah[3], bfrag[it][2], acc, 0, 0, 0);
                acc = __builtin_amdgcn_mfma_f32_16x16x32_f16(al3,  bfrag[it][2], acc, 0, 0, 0);
                // C/D layout: col(n) = lane&15, row(seq) = quad*4 + r.
                // Pack 4 gates (4 seqs, same n) to f16 RNE, one ds_write_b64.
                uintx2 pk;
                pk.x = (unsigned)f32_to_f16u(acc[0]) | ((unsigned)f32_to_f16u(acc[1]) << 16);
                pk.y = (unsigned)f32_to_f16u(acc[2]) | ((unsigned)f32_to_f16u(acc[3]) << 16);
                *(uintx2*)&s_g16[(tile * 16 + m) * GSTR + quad * 4] = pk;
            }
        }
        __syncthreads();   // barrier 2: gates ready

        const bool last = (t == T_STEPS - 1);
#pragma unroll
        for (int u = 0; u < 6; ++u) {
            int j = j0 + u * 16;              // j in 0..95, all threads unconditional
            float gi = f16u_to_f32(s_g16[j * GSTR + us]);
            float gf = f16u_to_f32(s_g16[(100 + j) * GSTR + us]);
            float gg = f16u_to_f32(s_g16[(200 + j) * GSTR + us]);
            float go = f16u_to_f32(s_g16[(300 + j) * GSTR + us]);
            float c  = fsigm(gf) * c_reg[u] + fsigm(gi) * ftanh(gg);
            c_reg[u] = c;
            float h  = fsigm(go) * ftanh(c);
            if (!last) {
                s_A[us * KSTR + j] = f32_to_f16u(h);    // h as f16 (hi only)
            } else {
                out[(size_t)(seq0 + us) * H_UNITS + j] = h;
            }
        }
        if (tid >= 192) {                     // units j = 96..99
            int d = tid - 192;
            int s = d & 15, j = 96 + (d >> 4);
            float gi = f16u_to_f32(s_g16[j * GSTR + s]);
            float gf = f16u_to_f32(s_g16[(100 + j) * GSTR + s]);
            float gg = f16u_to_f32(s_g16[(200 + j) * GSTR + s]);
            float go = f16u_to_f32(s_g16[(300 + j) * GSTR + s]);
            float c  = fsigm(gf) * c6 + fsigm(gi) * ftanh(gg);
            c6 = c;
            float h  = fsigm(go) * ftanh(c);
            if (!last) {
                s_A[s * KSTR + j] = f32_to_f16u(h);
            } else {
                out[(size_t)(seq0 + s) * H_UNITS + j] = h;
            }
        }
        if (tid < 128 && !last) {             // refresh x(t+1) cols 100..107
            unsigned short hi = f32_to_f16u(xnext);
            if (rc < 4) {
                s_A[rs * KSTR + 100 + rc]        = hi;
                s_A[(16 + rs) * KSTR + 100 + rc] = f32_to_f16u(xnext - f16u_to_f32(hi));
            } else {
                s_A[(16 + rs) * KSTR + 100 + rc] = hi;
            }
        }
    }
}

extern "C" void kernel_launch(void* const* d_in, const int* in_sizes, int n_in,
                              void* d_out, int out_size, void* d_ws, size_t ws_size,
                              hipStream_t stream) {
    const float* x    = (const float*)d_in[0];   // [4096,3,128,4]
    const float* W_ih = (const float*)d_in[1];   // [400,4]
    const float* W_hh = (const float*)d_in[2];   // [400,100]
    const float* b_ih = (const float*)d_in[3];   // [400]
    const float* b_hh = (const float*)d_in[4];   // [400]
    ushortx8* Bpack = (ushortx8*)d_ws;           // 25*4*64*16 B = 102,400 B

    lstm_prep_pack<<<25, 256, 0, stream>>>(W_ih, W_hh, b_ih, b_hh, Bpack);
    lstm_main<<<NBLK, 256, 0, stream>>>(x, Bpack, (float*)d_out);
}

// Round 8
// 335.897 us; speedup vs baseline: 1.1998x; 1.1795x over previous
//
#include <hip/hip_runtime.h>
#include <cstdint>

// ShortTermLSTM on MI355X: batched LSTM, transposed-GEMM f16 MFMA, cell fully
// in registers.
// R1 (569us): h-side=A, W-side=B, 8 MFMA/tile, absmax 1.95e-3.
// R2/R3 (failed): legacy 16x16x16f16 B-layout != k=quad*4+j. Reverted.
// R4 (444us): s_x removed, global x prefetch. R5 (370us): h f16-only, 5 MFMA/tile.
// R6 (403us): DPP-transpose cell — VALU too costly; verified gate-interleave
//   permutation. R7 (396us): kc0->LDS, f16 gates; occupancy STUCK at ~2.28
//   blocks/CU => hidden limit, hypothesis: effective LDS pool ~128KB.
// R8: TRANSPOSED GEMM. D = W_tile(A-operand) x h(B-operand). With row
//   permutation row_loc=4u+g, C/D layout (col=lane&15=seq, row=quad*4+reg)
//   puts {i,f,g,o} of unit (j=tile*4+quad, s=lane&15) into one lane's 4 acc
//   regs. Cell in registers; s_g + barrier2 + epilogue LDS reads deleted;
//   ONE barrier/step, ping-pong s_A. LDS 43,008 B -> 3 blocks/CU even if the
//   pool is 128KB; regs ~168 (84 AGPR W-frags kc1..3 + kc0 in LDS).
//
// Per step: gates[400,16] = W[400,128] x A[128,16]:
//   h-side rows (LDS, [seq][k], hi|lo):
//     hi k 0..99: f16(h) | hi k 100..103: x_hi | hi k 108: 1.0
//     lo k 100..103: x_lo | lo k 104..107: x_hi (W_lo route) | lo k 109: 1.0
//     all else 0 (h_lo dropped; error ~6e-5/step, measured margin 4x)
//   W-side (regs/LDS, A-operand frags): rows permuted g*100 + tile*4 + u.
// 5 MFMAs/tile: 4 hi (kc0..3) + 1 lo (kc3 W reused).

#define H_UNITS 100
#define T_STEPS 128
#define S_BLK   16
#define NSEQ    12288
#define NBLK    (NSEQ / S_BLK)   // 768
#define NTILE   25               // 100 units / 4 per tile
#define KSTR    136              // LDS h row stride (ushorts): 8-phase-ideal b128 reads

typedef __attribute__((ext_vector_type(8))) _Float16 halfx8;
typedef __attribute__((ext_vector_type(8))) unsigned short ushortx8;
typedef __attribute__((ext_vector_type(4))) float floatx4;

__device__ __forceinline__ unsigned short f32_to_f16u(float x) {
    _Float16 h = (_Float16)x;                       // v_cvt_f16_f32 (RNE)
    return __builtin_bit_cast(unsigned short, h);
}
__device__ __forceinline__ float f16u_to_f32(unsigned short u) {
    _Float16 h = __builtin_bit_cast(_Float16, u);
    return (float)h;
}
__device__ __forceinline__ float fsigm(float x) {
    return __builtin_amdgcn_rcpf(1.0f + __expf(-x));
}
__device__ __forceinline__ float ftanh(float x) {
    // 1 - 2/(e^{2x}+1); exp->inf handled correctly (rcp(inf)=0)
    return 1.0f - 2.0f * __builtin_amdgcn_rcpf(1.0f + __expf(2.0f * x));
}

// ---------------------------------------------------------------------------
// Prep: pack W into MFMA A-operand fragment order with gate-interleaved rows:
//   frag elem (tile,kc,lane,j) = W[row = (m&3)*100 + tile*4 + (m>>2)][k = kc*32+quad*8+j]
//   where m = lane&15, quad = (lane>>4)&3.   (permutation verified in R6)
// ---------------------------------------------------------------------------
__global__ void lstm_prep_pack(const float* __restrict__ W_ih,
                               const float* __restrict__ W_hh,
                               const float* __restrict__ b_ih,
                               const float* __restrict__ b_hh,
                               ushortx8* __restrict__ Bpack) {
    int t = blockIdx.x * 256 + threadIdx.x;   // (tile,kc,lane) flattened: 25*4*64 = 6400
    if (t >= NTILE * 4 * 64) return;
    int lane = t & 63;
    int kc   = (t >> 6) & 3;
    int tile = t >> 8;
    int m    = lane & 15;
    int n  = (m & 3) * 100 + tile * 4 + (m >> 2);   // permuted gate row
    int k0 = kc * 32 + ((lane >> 4) & 3) * 8;
    ushortx8 v;
#pragma unroll
    for (int j = 0; j < 8; ++j) {
        int k = k0 + j;
        unsigned short w = 0;
        if (k < 100) {
            w = f32_to_f16u(W_hh[n * 100 + k]);
        } else if (k < 104) {
            w = f32_to_f16u(W_ih[n * 4 + (k - 100)]);
        } else if (k < 108) {
            float wf = W_ih[n * 4 + (k - 104)];
            unsigned short hi = f32_to_f16u(wf);
            w = f32_to_f16u(wf - f16u_to_f32(hi));
        } else if (k == 108) {
            float b = b_ih[n] + b_hh[n];
            w = f32_to_f16u(b);
        } else if (k == 109) {
            float b = b_ih[n] + b_hh[n];
            unsigned short hi = f32_to_f16u(b);
            w = f32_to_f16u(b - f16u_to_f32(hi));
        }
        v[j] = w;
    }
    Bpack[t] = v;
}

// ---------------------------------------------------------------------------
// Main: one block = 16 sequences, full T loop. 4 waves; wave w owns tiles
// {w, w+4, ...}. Lane cell: unit j = tile*4 + quad, seq s = lane&15,
// acc regs = {i,f,g,o}. W kc1..3 frags in regs (84 AGPR); kc0 in LDS.
// ---------------------------------------------------------------------------
__global__ void __launch_bounds__(256, 3)
lstm_main(const float* __restrict__ x, const ushortx8* __restrict__ Bpack,
          float* __restrict__ out) {
    __shared__ __align__(16) unsigned short s_A[2][2 * 16 * KSTR];   // ping-pong, 2 x 8704 B
    __shared__ __align__(16) ushortx8       s_Wk0[NTILE * 64];       // 25600 B, kc0 W-frags

    const int tid  = threadIdx.x;
    const int lane = tid & 63;
    const int wave = tid >> 6;
    const int seq0 = blockIdx.x * S_BLK;
    const int m    = lane & 15;
    const int quad = lane >> 4;

    // ---- W fragments kc1..3: global -> regs, once (84 regs/wave)
    halfx8 wfrag[7][3];
#pragma unroll
    for (int it = 0; it < 7; ++it) {
        int tile = wave + it * 4;
        if (tile < NTILE) {
#pragma unroll
            for (int kc = 0; kc < 3; ++kc)
                wfrag[it][kc] = __builtin_bit_cast(halfx8, Bpack[(tile * 4 + kc + 1) * 64 + lane]);
        }
    }
    // ---- kc0 W-frags: global -> LDS, once
    for (int i = tid; i < NTILE * 64; i += 256)
        s_Wk0[i] = Bpack[(i >> 6) * 256 + (i & 63)];

    // refresh-thread x pointer (valid for tid < 128): (s = tid&15, cc = tid>>4)
    const int rs = tid & 15, rc = tid >> 4;
    const float* xb = x + (size_t)(seq0 + rs) * (T_STEPS * 4) + (rc & 3);

    // ---- zero both buffers (h(0)=0; pads and lo k0..99 stay 0 forever)
    for (int i = tid; i < (2 * 2 * 16 * KSTR) / 2; i += 256)
        ((unsigned int*)s_A)[i] = 0u;
    float x0 = 0.0f;
    if (tid < 128) x0 = xb[0];
    __syncthreads();
    // ---- x(t=0) into buf0; constant bias-select cols into BOTH buffers
    if (tid < 128) {
        unsigned short hi = f32_to_f16u(x0);
        if (rc < 4) {
            s_A[0][rs * KSTR + 100 + rc]        = hi;                                // hi = x_hi
            s_A[0][(16 + rs) * KSTR + 100 + rc] = f32_to_f16u(x0 - f16u_to_f32(hi)); // lo = x_lo
        } else {
            s_A[0][(16 + rs) * KSTR + 100 + rc] = hi;                                // lo = x_hi (W_lo)
        }
    } else if (tid < 160) {
        int d = tid - 128;                     // (buf, s) for k=108
        s_A[d >> 4][(d & 15) * KSTR + 108] = 0x3C00;          // hi k108 = 1.0
    } else if (tid < 192) {
        int d = tid - 160;                     // (buf, s) for k=109
        s_A[d >> 4][(16 + (d & 15)) * KSTR + 109] = 0x3C00;   // lo k109 = 1.0
    }

    float c_reg[7];
#pragma unroll
    for (int it = 0; it < 7; ++it) c_reg[it] = 0.0f;

    const int aOffHi = m * KSTR + quad * 8;
    const int aOffLo = (16 + m) * KSTR + 96 + quad * 8;

    for (int t = 0; t < T_STEPS; ++t) {
        const int bR = t & 1;
        // prefetch x(t+1) — issued before MFMA phase to hide latency
        float xnext = 0.0f;
        if (tid < 128) {
            int tn = t + 1; if (tn > T_STEPS - 1) tn = T_STEPS - 1;
            xnext = xb[tn * 4];
        }
        __syncthreads();   // ONE barrier/step: buf[bR] (h(t), x(t)) ready

        const unsigned short* base  = s_A[bR];
        unsigned short*       baseW = s_A[bR ^ 1];
        halfx8 hh[4], hl3;
#pragma unroll
        for (int kc = 0; kc < 4; ++kc)
            hh[kc] = *(const halfx8*)(base + aOffHi + kc * 32);   // ds_read_b128
        hl3 = *(const halfx8*)(base + aOffLo);

        const bool last = (t == T_STEPS - 1);
#pragma unroll
        for (int it = 0; it < 7; ++it) {
            int tile = wave + it * 4;
            if (tile < NTILE) {
                halfx8 w0 = __builtin_bit_cast(halfx8, s_Wk0[tile * 64 + lane]);  // kc0 W-frag
                floatx4 acc = {0.0f, 0.0f, 0.0f, 0.0f};
                acc = __builtin_amdgcn_mfma_f32_16x16x32_f16(w0,           hh[0], acc, 0, 0, 0);
                acc = __builtin_amdgcn_mfma_f32_16x16x32_f16(wfrag[it][0], hh[1], acc, 0, 0, 0);
                acc = __builtin_amdgcn_mfma_f32_16x16x32_f16(wfrag[it][1], hh[2], acc, 0, 0, 0);
                acc = __builtin_amdgcn_mfma_f32_16x16x32_f16(wfrag[it][2], hh[3], acc, 0, 0, 0);
                acc = __builtin_amdgcn_mfma_f32_16x16x32_f16(wfrag[it][2], hl3,  acc, 0, 0, 0);
                // lane = (seq s=m, unit j=tile*4+quad); acc = {i, f, g, o}
                float c = fsigm(acc[1]) * c_reg[it] + fsigm(acc[0]) * ftanh(acc[2]);
                c_reg[it] = c;
                float h = fsigm(acc[3]) * ftanh(c);
                int j = tile * 4 + quad;
                if (!last) {
                    baseW[m * KSTR + j] = f32_to_f16u(h);    // h(t+1) f16 -> other buffer
                } else {
                    out[(size_t)(seq0 + m) * H_UNITS + j] = h;
                }
            }
        }
        if (tid < 128 && !last) {             // x(t+1) k100..107 -> other buffer
            unsigned short hi = f32_to_f16u(xnext);
            if (rc < 4) {
                baseW[rs * KSTR + 100 + rc]        = hi;
                baseW[(16 + rs) * KSTR + 100 + rc] = f32_to_f16u(xnext - f16u_to_f32(hi));
            } else {
                baseW[(16 + rs) * KSTR + 100 + rc] = hi;
            }
        }
    }
}

extern "C" void kernel_launch(void* const* d_in, const int* in_sizes, int n_in,
                              void* d_out, int out_size, void* d_ws, size_t ws_size,
                              hipStream_t stream) {
    const float* x    = (const float*)d_in[0];   // [4096,3,128,4]
    const float* W_ih = (const float*)d_in[1];   // [400,4]
    const float* W_hh = (const float*)d_in[2];   // [400,100]
    const float* b_ih = (const float*)d_in[3];   // [400]
    const float* b_hh = (const float*)d_in[4];   // [400]
    ushortx8* Bpack = (ushortx8*)d_ws;           // 25*4*64*16 B = 102,400 B

    lstm_prep_pack<<<25, 256, 0, stream>>>(W_ih, W_hh, b_ih, b_hh, Bpack);
    lstm_main<<<NBLK, 256, 0, stream>>>(x, Bpack, (float*)d_out);
}

// Round 10
// 324.449 us; speedup vs baseline: 1.2421x; 1.0353x over previous
//
#include <hip/hip_runtime.h>
#include <cstdint>

// ShortTermLSTM on MI355X: batched LSTM, transposed-GEMM f16 MFMA, cell fully
// in registers, fused-rcp activations.
// R1 (569us) h=A-side baseline. R2/R3 failed legacy-intrinsic B-layout.
// R4 (444us) global x prefetch. R5 (370us) h f16-only. R6 (403us) DPP cell
//   (reverted; verified gate-interleave permutation). R7 (396us) kc0->LDS.
// R8 (336us): TRANSPOSED GEMM, {i,f,g,o} of one unit land in one lane's acc
//   regs; one barrier/step; passed full harness.
// R9 (322us, FAILED replay tripwire): fused-rcp cell (10->7 trans), 4 MFMA/tile
//   (x_lo rides spare K cols w/ W_hi copy), branch-free loop split. First
//   launch passed; replays + subsequent fresh launches consistently diverged
//   (0.36) -> timing/scheduling-sensitive element, not a math bug.
// R10: R9 + SECOND __syncthreads() at loop bottom (write-phase fence; the
//   two-barrier structure proven in R1/R4/R5/R7). Keeps all R9 wins.
//
// A[16][128] per step (ping-pong LDS):
//   k  0.. 99: f16(h)      -> W = f16(W_hh)
//   k100..103: x_hi        -> W = W_ih_hi
//   k104..107: x_lo        -> W = W_ih_hi (copy)
//   k108..111: x_hi        -> W = W_ih_lo = f16(W_ih - W_ih_hi)
//   k112     : 1.0         -> W = b_hi = f16(b_ih + b_hh)
//   k113     : 1.0         -> W = b_lo = f16(b - b_hi)
//   k114..127: 0 (never written)
// Residual error: dropped h*W_hh_lo (~6e-5/step); measured margin ~4x.

#define H_UNITS 100
#define T_STEPS 128
#define S_BLK   16
#define NSEQ    12288
#define NBLK    (NSEQ / S_BLK)   // 768
#define NTILE   25               // 100 units / 4 per tile
#define KSTR    136              // LDS h row stride (ushorts): 8-phase-ideal b128 reads

typedef __attribute__((ext_vector_type(8))) _Float16 halfx8;
typedef __attribute__((ext_vector_type(8))) unsigned short ushortx8;
typedef __attribute__((ext_vector_type(4))) float floatx4;

__device__ __forceinline__ unsigned short f32_to_f16u(float x) {
    _Float16 h = (_Float16)x;                       // v_cvt_f16_f32 (RNE)
    return __builtin_bit_cast(unsigned short, h);
}
__device__ __forceinline__ float f16u_to_f32(unsigned short u) {
    _Float16 h = __builtin_bit_cast(_Float16, u);
    return (float)h;
}

// ---------------------------------------------------------------------------
// Prep: pack W into MFMA A-operand fragment order with gate-interleaved rows:
//   frag elem (tile,kc,lane,j) = W[row = (m&3)*100 + tile*4 + (m>>2)][k]
//   k = kc*32 + quad*8 + j, m = lane&15, quad = (lane>>4)&3.
// ---------------------------------------------------------------------------
__global__ void lstm_prep_pack(const float* __restrict__ W_ih,
                               const float* __restrict__ W_hh,
                               const float* __restrict__ b_ih,
                               const float* __restrict__ b_hh,
                               ushortx8* __restrict__ Bpack) {
    int t = blockIdx.x * 256 + threadIdx.x;   // (tile,kc,lane) flattened: 25*4*64 = 6400
    if (t >= NTILE * 4 * 64) return;
    int lane = t & 63;
    int kc   = (t >> 6) & 3;
    int tile = t >> 8;
    int m    = lane & 15;
    int n  = (m & 3) * 100 + tile * 4 + (m >> 2);   // permuted gate row (i,f,g,o = m&3)
    int k0 = kc * 32 + ((lane >> 4) & 3) * 8;
    ushortx8 v;
#pragma unroll
    for (int j = 0; j < 8; ++j) {
        int k = k0 + j;
        unsigned short w = 0;
        if (k < 100) {
            w = f32_to_f16u(W_hh[n * 100 + k]);
        } else if (k < 108) {                     // k100-103 AND k104-107: W_ih_hi
            w = f32_to_f16u(W_ih[n * 4 + ((k - 100) & 3)]);
        } else if (k < 112) {                     // k108-111: W_ih_lo
            float wf = W_ih[n * 4 + (k - 108)];
            unsigned short hi = f32_to_f16u(wf);
            w = f32_to_f16u(wf - f16u_to_f32(hi));
        } else if (k == 112) {                    // b_hi
            float b = b_ih[n] + b_hh[n];
            w = f32_to_f16u(b);
        } else if (k == 113) {                    // b_lo
            float b = b_ih[n] + b_hh[n];
            unsigned short hi = f32_to_f16u(b);
            w = f32_to_f16u(b - f16u_to_f32(hi));
        }
        v[j] = w;
    }
    Bpack[t] = v;
}

// ---------------------------------------------------------------------------
// Main: one block = 16 sequences, full T loop. 4 waves; waves do tiles
// {w, w+4, ..., w+20} branch-free, wave0 additionally tile 24.
// Lane cell: unit j = tile*4 + quad, seq s = lane&15, acc = {i,f,g,o}.
// W kc1..3 frags in regs (84); kc0 in LDS. TWO barriers per timestep.
// ---------------------------------------------------------------------------
__global__ void __launch_bounds__(256, 3)
lstm_main(const float* __restrict__ x, const ushortx8* __restrict__ Bpack,
          float* __restrict__ out) {
    __shared__ __align__(16) unsigned short s_A[2][16 * KSTR];   // ping-pong, 2 x 4352 B
    __shared__ __align__(16) ushortx8       s_Wk0[NTILE * 64];   // 25600 B, kc0 W-frags

    const int tid  = threadIdx.x;
    const int lane = tid & 63;
    const int wave = tid >> 6;
    const int seq0 = blockIdx.x * S_BLK;
    const int m    = lane & 15;
    const int quad = lane >> 4;

    // ---- W fragments kc1..3: global -> regs, once (84 regs/wave)
    halfx8 wfrag[7][3];
#pragma unroll
    for (int it = 0; it < 7; ++it) {
        int tile = wave + it * 4;
        if (tile < NTILE) {
#pragma unroll
            for (int kc = 0; kc < 3; ++kc)
                wfrag[it][kc] = __builtin_bit_cast(halfx8, Bpack[(tile * 4 + kc + 1) * 64 + lane]);
        }
    }
    // ---- kc0 W-frags: global -> LDS, once
    for (int i = tid; i < NTILE * 64; i += 256)
        s_Wk0[i] = Bpack[(i >> 6) * 256 + (i & 63)];

    // refresh-thread x pointer (valid for tid < 128): (s = tid&15, cc = tid>>4)
    const int rs = tid & 15, rc = tid >> 4;
    const float* xb = x + (size_t)(seq0 + rs) * (T_STEPS * 4) + (rc & 3);

    // ---- zero both buffers (h(0)=0; k114-127 stay 0 forever)
    for (int i = tid; i < (2 * 16 * KSTR) / 2; i += 256)
        ((unsigned int*)s_A)[i] = 0u;
    float x0 = 0.0f;
    if (tid < 128) x0 = xb[0];
    __syncthreads();
    // ---- x(t=0) into buf0; constant bias-select cols into BOTH buffers
    if (tid < 128) {
        if (rc < 4) {
            unsigned short hi = f32_to_f16u(x0);
            s_A[0][rs * KSTR + 100 + rc] = hi;    // x_hi (W_hi route)
            s_A[0][rs * KSTR + 108 + rc] = hi;    // x_hi (W_lo route)
        } else {
            float xv = x0;
            unsigned short hi = f32_to_f16u(xv);
            s_A[0][rs * KSTR + 104 + (rc - 4)] = f32_to_f16u(xv - f16u_to_f32(hi)); // x_lo
        }
    } else if (tid < 160) {
        int d = tid - 128;                     // (buf, s) for k=112
        s_A[d >> 4][(d & 15) * KSTR + 112] = 0x3C00;
    } else if (tid < 192) {
        int d = tid - 160;                     // (buf, s) for k=113
        s_A[d >> 4][(d & 15) * KSTR + 113] = 0x3C00;
    }

    float c_reg[6];
#pragma unroll
    for (int it = 0; it < 6; ++it) c_reg[it] = 0.0f;
    float c24 = 0.0f;

    const int aOff = m * KSTR + quad * 8;

    for (int t = 0; t < T_STEPS; ++t) {
        const int bR = t & 1;
        // prefetch x(t+1) — issued before MFMA phase to hide latency
        float xnext = 0.0f;
        if (tid < 128) {
            int tn = t + 1; if (tn > T_STEPS - 1) tn = T_STEPS - 1;
            xnext = xb[tn * 4];
        }
        __syncthreads();   // barrier 1: buf[bR] (h(t), x(t)) ready

        const unsigned short* base  = s_A[bR];
        unsigned short*       baseW = s_A[bR ^ 1];
        halfx8 hh[4];
#pragma unroll
        for (int kc = 0; kc < 4; ++kc)
            hh[kc] = *(const halfx8*)(base + aOff + kc * 32);   // ds_read_b128

        const bool last = (t == T_STEPS - 1);

        auto docell = [&](int tile, halfx8 w1, halfx8 w2, halfx8 w3, float& cm) {
            halfx8 w0 = __builtin_bit_cast(halfx8, s_Wk0[tile * 64 + lane]);  // kc0 frag
            floatx4 acc = {0.0f, 0.0f, 0.0f, 0.0f};
            acc = __builtin_amdgcn_mfma_f32_16x16x32_f16(w0, hh[0], acc, 0, 0, 0);
            acc = __builtin_amdgcn_mfma_f32_16x16x32_f16(w1, hh[1], acc, 0, 0, 0);
            acc = __builtin_amdgcn_mfma_f32_16x16x32_f16(w2, hh[2], acc, 0, 0, 0);
            acc = __builtin_amdgcn_mfma_f32_16x16x32_f16(w3, hh[3], acc, 0, 0, 0);
            // lane = (seq s=m, unit j=tile*4+quad); acc = {i, f, g, o}
            // Fused-rcp cell: sigm(f)c + sigm(i)tanh(g) = num/(a*b*d), one rcp.
            float ei = __expf(acc[0]);
            float ef = __expf(acc[1]);
            float eg = __expf(2.0f * acc[2]);
            float eo = __expf(acc[3]);
            float a  = 1.0f + ei, b = 1.0f + ef;
            float d  = eg + 1.0f, e2 = eg - 1.0f;
            float q  = a * d;
            float r  = __builtin_amdgcn_rcpf(q * b);
            float nm = fmaf(ef * q, cm, (ei * b) * e2);
            float c  = nm * r;
            cm = c;
            float cc = fminf(c, 40.0f);          // e^{2c} overflow guard; c<<0 degrades gracefully
            float ec = __expf(2.0f * cc);
            float r2 = __builtin_amdgcn_rcpf((1.0f + eo) * (ec + 1.0f));
            float h  = (eo * (ec - 1.0f)) * r2;
            int j = tile * 4 + quad;
            if (!last) {
                baseW[m * KSTR + j] = f32_to_f16u(h);    // h(t+1) f16 -> other buffer
            } else {
                out[(size_t)(seq0 + m) * H_UNITS + j] = h;
            }
        };

#pragma unroll
        for (int it = 0; it < 6; ++it)           // tiles 0..23: branch-free
            docell(wave + it * 4, wfrag[it][0], wfrag[it][1], wfrag[it][2], c_reg[it]);
        if (wave == 0)                           // tile 24: wave0 only
            docell(24, wfrag[6][0], wfrag[6][1], wfrag[6][2], c24);

        if (tid < 128 && !last) {                // x(t+1) k100..111 -> other buffer
            if (rc < 4) {
                unsigned short hi = f32_to_f16u(xnext);
                baseW[rs * KSTR + 100 + rc] = hi;
                baseW[rs * KSTR + 108 + rc] = hi;
            } else {
                unsigned short hi = f32_to_f16u(xnext);
                baseW[rs * KSTR + 104 + (rc - 4)] = f32_to_f16u(xnext - f16u_to_f32(hi));
            }
        }
        __syncthreads();   // barrier 2: write-phase fence (R10 hardening)
    }
}

extern "C" void kernel_launch(void* const* d_in, const int* in_sizes, int n_in,
                              void* d_out, int out_size, void* d_ws, size_t ws_size,
                              hipStream_t stream) {
    const float* x    = (const float*)d_in[0];   // [4096,3,128,4]
    const float* W_ih = (const float*)d_in[1];   // [400,4]
    const float* W_hh = (const float*)d_in[2];   // [400,100]
    const float* b_ih = (const float*)d_in[3];   // [400]
    const float* b_hh = (const float*)d_in[4];   // [400]
    ushortx8* Bpack = (ushortx8*)d_ws;           // 25*4*64*16 B = 102,400 B

    lstm_prep_pack<<<25, 256, 0, stream>>>(W_ih, W_hh, b_ih, b_hh, Bpack);
    lstm_main<<<NBLK, 256, 0, stream>>>(x, Bpack, (float*)d_out);
}

// Round 11
// 321.440 us; speedup vs baseline: 1.2537x; 1.0094x over previous
//
#include <hip/hip_runtime.h>
#include <cstdint>

// ShortTermLSTM on MI355X: batched LSTM, transposed-GEMM f16 MFMA, cell fully
// in registers, fused-rcp activations.
// R1 (569us) h=A-side baseline. R2/R3 failed legacy-intrinsic B-layout.
// R4 (444us) global x prefetch. R5 (370us) h f16-only. R6 (403us) DPP cell
//   (reverted; verified gate-interleave permutation). R7 (396us) kc0->LDS.
// R8 (336us): TRANSPOSED GEMM, {i,f,g,o} of one unit in one lane's acc regs.
// R9 (322us, replay-diverged): fused-rcp cell, 4 MFMA/tile. R10 (324us,
//   steady 292): R9 + write-phase fence barrier -> stable. Occupancy STILL
//   ~2.1 blocks/CU across R4-R10 despite nominal 160 regs <= 170.
// R11: register-quantum hypothesis test. If VGPR/AGPR each round to 16:
//   80+96=176 > 170 -> only 2 waves/SIMD granted. Move tile-24 kc1..3 frags
//   to LDS: AGPR 84->72; worst-case 80+80=160 <= 170 -> 3 waves/SIMD robust.
//   LDS 37,376 B (x3 = 112K ok). Math bit-identical to R10.
//
// A[16][128] per step (ping-pong LDS):
//   k  0.. 99: f16(h)      -> W = f16(W_hh)
//   k100..103: x_hi        -> W = W_ih_hi
//   k104..107: x_lo        -> W = W_ih_hi (copy)
//   k108..111: x_hi        -> W = W_ih_lo = f16(W_ih - W_ih_hi)
//   k112     : 1.0         -> W = b_hi = f16(b_ih + b_hh)
//   k113     : 1.0         -> W = b_lo = f16(b - b_hi)
//   k114..127: 0 (never written)
// Residual error: dropped h*W_hh_lo (~6e-5/step); measured margin ~4x.

#define H_UNITS 100
#define T_STEPS 128
#define S_BLK   16
#define NSEQ    12288
#define NBLK    (NSEQ / S_BLK)   // 768
#define NTILE   25               // 100 units / 4 per tile
#define KSTR    136              // LDS h row stride (ushorts): 8-phase-ideal b128 reads
#define WEXT    (NTILE * 64)     // offset of tile-24 kc1..3 frags in s_W

typedef __attribute__((ext_vector_type(8))) _Float16 halfx8;
typedef __attribute__((ext_vector_type(8))) unsigned short ushortx8;
typedef __attribute__((ext_vector_type(4))) float floatx4;

__device__ __forceinline__ unsigned short f32_to_f16u(float x) {
    _Float16 h = (_Float16)x;                       // v_cvt_f16_f32 (RNE)
    return __builtin_bit_cast(unsigned short, h);
}
__device__ __forceinline__ float f16u_to_f32(unsigned short u) {
    _Float16 h = __builtin_bit_cast(_Float16, u);
    return (float)h;
}

// ---------------------------------------------------------------------------
// Prep: pack W into MFMA A-operand fragment order with gate-interleaved rows:
//   frag elem (tile,kc,lane,j) = W[row = (m&3)*100 + tile*4 + (m>>2)][k]
//   k = kc*32 + quad*8 + j, m = lane&15, quad = (lane>>4)&3.
// ---------------------------------------------------------------------------
__global__ void lstm_prep_pack(const float* __restrict__ W_ih,
                               const float* __restrict__ W_hh,
                               const float* __restrict__ b_ih,
                               const float* __restrict__ b_hh,
                               ushortx8* __restrict__ Bpack) {
    int t = blockIdx.x * 256 + threadIdx.x;   // (tile,kc,lane) flattened: 25*4*64 = 6400
    if (t >= NTILE * 4 * 64) return;
    int lane = t & 63;
    int kc   = (t >> 6) & 3;
    int tile = t >> 8;
    int m    = lane & 15;
    int n  = (m & 3) * 100 + tile * 4 + (m >> 2);   // permuted gate row (i,f,g,o = m&3)
    int k0 = kc * 32 + ((lane >> 4) & 3) * 8;
    ushortx8 v;
#pragma unroll
    for (int j = 0; j < 8; ++j) {
        int k = k0 + j;
        unsigned short w = 0;
        if (k < 100) {
            w = f32_to_f16u(W_hh[n * 100 + k]);
        } else if (k < 108) {                     // k100-103 AND k104-107: W_ih_hi
            w = f32_to_f16u(W_ih[n * 4 + ((k - 100) & 3)]);
        } else if (k < 112) {                     // k108-111: W_ih_lo
            float wf = W_ih[n * 4 + (k - 108)];
            unsigned short hi = f32_to_f16u(wf);
            w = f32_to_f16u(wf - f16u_to_f32(hi));
        } else if (k == 112) {                    // b_hi
            float b = b_ih[n] + b_hh[n];
            w = f32_to_f16u(b);
        } else if (k == 113) {                    // b_lo
            float b = b_ih[n] + b_hh[n];
            unsigned short hi = f32_to_f16u(b);
            w = f32_to_f16u(b - f16u_to_f32(hi));
        }
        v[j] = w;
    }
    Bpack[t] = v;
}

// ---------------------------------------------------------------------------
// Main: one block = 16 sequences, full T loop. 4 waves; waves do tiles
// {w, w+4, ..., w+20} branch-free, wave0 additionally tile 24 (its kc1..3
// frags come from LDS). Lane cell: unit j = tile*4 + quad, seq s = lane&15,
// acc = {i,f,g,o}. W kc1..3 of tiles 0..23 in regs (72); kc0 + tile24-kc123
// in LDS. TWO barriers per timestep.
// ---------------------------------------------------------------------------
__global__ void __launch_bounds__(256, 3)
lstm_main(const float* __restrict__ x, const ushortx8* __restrict__ Bpack,
          float* __restrict__ out) {
    __shared__ __align__(16) unsigned short s_A[2][16 * KSTR];   // ping-pong, 2 x 4352 B
    __shared__ __align__(16) ushortx8       s_W[WEXT + 3 * 64];  // 28672 B W-frags

    const int tid  = threadIdx.x;
    const int lane = tid & 63;
    const int wave = tid >> 6;
    const int seq0 = blockIdx.x * S_BLK;
    const int m    = lane & 15;
    const int quad = lane >> 4;

    // ---- W fragments kc1..3 of tiles 0..23: global -> regs, once (72 regs)
    halfx8 wfrag[6][3];
#pragma unroll
    for (int it = 0; it < 6; ++it) {
        int tile = wave + it * 4;                 // <= 23, branch-free
#pragma unroll
        for (int kc = 0; kc < 3; ++kc)
            wfrag[it][kc] = __builtin_bit_cast(halfx8, Bpack[(tile * 4 + kc + 1) * 64 + lane]);
    }
    // ---- kc0 frags (all tiles) + tile-24 kc1..3: global -> LDS, once
    for (int i = tid; i < WEXT + 3 * 64; i += 256) {
        int idx;
        if (i < WEXT) idx = (i >> 6) * 256 + (i & 63);                 // tile i>>6, kc0
        else { int jj = i - WEXT; idx = (24 * 4 + 1 + (jj >> 6)) * 64 + (jj & 63); }
        s_W[i] = Bpack[idx];
    }

    // refresh-thread x pointer (valid for tid < 128): (s = tid&15, cc = tid>>4)
    const int rs = tid & 15, rc = tid >> 4;
    const float* xb = x + (size_t)(seq0 + rs) * (T_STEPS * 4) + (rc & 3);

    // ---- zero both buffers (h(0)=0; k114-127 stay 0 forever)
    for (int i = tid; i < (2 * 16 * KSTR) / 2; i += 256)
        ((unsigned int*)s_A)[i] = 0u;
    float x0 = 0.0f;
    if (tid < 128) x0 = xb[0];
    __syncthreads();
    // ---- x(t=0) into buf0; constant bias-select cols into BOTH buffers
    if (tid < 128) {
        if (rc < 4) {
            unsigned short hi = f32_to_f16u(x0);
            s_A[0][rs * KSTR + 100 + rc] = hi;    // x_hi (W_hi route)
            s_A[0][rs * KSTR + 108 + rc] = hi;    // x_hi (W_lo route)
        } else {
            float xv = x0;
            unsigned short hi = f32_to_f16u(xv);
            s_A[0][rs * KSTR + 104 + (rc - 4)] = f32_to_f16u(xv - f16u_to_f32(hi)); // x_lo
        }
    } else if (tid < 160) {
        int d = tid - 128;                     // (buf, s) for k=112
        s_A[d >> 4][(d & 15) * KSTR + 112] = 0x3C00;
    } else if (tid < 192) {
        int d = tid - 160;                     // (buf, s) for k=113
        s_A[d >> 4][(d & 15) * KSTR + 113] = 0x3C00;
    }

    float c_reg[6];
#pragma unroll
    for (int it = 0; it < 6; ++it) c_reg[it] = 0.0f;
    float c24 = 0.0f;

    const int aOff = m * KSTR + quad * 8;

    for (int t = 0; t < T_STEPS; ++t) {
        const int bR = t & 1;
        // prefetch x(t+1) — issued before MFMA phase to hide latency
        float xnext = 0.0f;
        if (tid < 128) {
            int tn = t + 1; if (tn > T_STEPS - 1) tn = T_STEPS - 1;
            xnext = xb[tn * 4];
        }
        __syncthreads();   // barrier 1: buf[bR] (h(t), x(t)) ready

        const unsigned short* base  = s_A[bR];
        unsigned short*       baseW = s_A[bR ^ 1];
        halfx8 hh[4];
#pragma unroll
        for (int kc = 0; kc < 4; ++kc)
            hh[kc] = *(const halfx8*)(base + aOff + kc * 32);   // ds_read_b128

        const bool last = (t == T_STEPS - 1);

        auto docell = [&](int tile, halfx8 w1, halfx8 w2, halfx8 w3, float& cm) {
            halfx8 w0 = __builtin_bit_cast(halfx8, s_W[tile * 64 + lane]);  // kc0 frag
            floatx4 acc = {0.0f, 0.0f, 0.0f, 0.0f};
            acc = __builtin_amdgcn_mfma_f32_16x16x32_f16(w0, hh[0], acc, 0, 0, 0);
            acc = __builtin_amdgcn_mfma_f32_16x16x32_f16(w1, hh[1], acc, 0, 0, 0);
            acc = __builtin_amdgcn_mfma_f32_16x16x32_f16(w2, hh[2], acc, 0, 0, 0);
            acc = __builtin_amdgcn_mfma_f32_16x16x32_f16(w3, hh[3], acc, 0, 0, 0);
            // lane = (seq s=m, unit j=tile*4+quad); acc = {i, f, g, o}
            // Fused-rcp cell: sigm(f)c + sigm(i)tanh(g) = num/(a*b*d), one rcp.
            float ei = __expf(acc[0]);
            float ef = __expf(acc[1]);
            float eg = __expf(2.0f * acc[2]);
            float eo = __expf(acc[3]);
            float a  = 1.0f + ei, b = 1.0f + ef;
            float d  = eg + 1.0f, e2 = eg - 1.0f;
            float q  = a * d;
            float r  = __builtin_amdgcn_rcpf(q * b);
            float nm = fmaf(ef * q, cm, (ei * b) * e2);
            float c  = nm * r;
            cm = c;
            float cc = fminf(c, 40.0f);          // e^{2c} overflow guard; c<<0 degrades gracefully
            float ec = __expf(2.0f * cc);
            float r2 = __builtin_amdgcn_rcpf((1.0f + eo) * (ec + 1.0f));
            float h  = (eo * (ec - 1.0f)) * r2;
            int j = tile * 4 + quad;
            if (!last) {
                baseW[m * KSTR + j] = f32_to_f16u(h);    // h(t+1) f16 -> other buffer
            } else {
                out[(size_t)(seq0 + m) * H_UNITS + j] = h;
            }
        };

#pragma unroll
        for (int it = 0; it < 6; ++it)           // tiles 0..23: branch-free
            docell(wave + it * 4, wfrag[it][0], wfrag[it][1], wfrag[it][2], c_reg[it]);
        if (wave == 0) {                         // tile 24: wave0 only, frags from LDS
            halfx8 w1 = __builtin_bit_cast(halfx8, s_W[WEXT + 0 * 64 + lane]);
            halfx8 w2 = __builtin_bit_cast(halfx8, s_W[WEXT + 1 * 64 + lane]);
            halfx8 w3 = __builtin_bit_cast(halfx8, s_W[WEXT + 2 * 64 + lane]);
            docell(24, w1, w2, w3, c24);
        }

        if (tid < 128 && !last) {                // x(t+1) k100..111 -> other buffer
            if (rc < 4) {
                unsigned short hi = f32_to_f16u(xnext);
                baseW[rs * KSTR + 100 + rc] = hi;
                baseW[rs * KSTR + 108 + rc] = hi;
            } else {
                unsigned short hi = f32_to_f16u(xnext);
                baseW[rs * KSTR + 104 + (rc - 4)] = f32_to_f16u(xnext - f16u_to_f32(hi));
            }
        }
        __syncthreads();   // barrier 2: write-phase fence
    }
}

extern "C" void kernel_launch(void* const* d_in, const int* in_sizes, int n_in,
                              void* d_out, int out_size, void* d_ws, size_t ws_size,
                              hipStream_t stream) {
    const float* x    = (const float*)d_in[0];   // [4096,3,128,4]
    const float* W_ih = (const float*)d_in[1];   // [400,4]
    const float* W_hh = (const float*)d_in[2];   // [400,100]
    const float* b_ih = (const float*)d_in[3];   // [400]
    const float* b_hh = (const float*)d_in[4];   // [400]
    ushortx8* Bpack = (ushortx8*)d_ws;           // 25*4*64*16 B = 102,400 B

    lstm_prep_pack<<<25, 256, 0, stream>>>(W_ih, W_hh, b_ih, b_hh, Bpack);
    lstm_main<<<NBLK, 256, 0, stream>>>(x, Bpack, (float*)d_out);
}